// Round 10
// baseline (229.875 us; speedup 1.0000x reference)
//
#include <hip/hip_runtime.h>

// Problem constants (fixed by the reference)
constexpr int CH    = 384;    // channels
constexpr int NPIX  = 1024;   // H*W = 32*32
constexpr int NHEAD = 12;
constexpr int DH    = 32;     // head dim
constexpr int NB    = 16;     // batch
constexpr float SCALE = 0.17677669529663689f;  // 32^-0.5
constexpr float LOG2E = 1.4426950408889634f;

typedef __attribute__((ext_vector_type(8))) short bf16x8;  // 8 bf16 (4 VGPRs)
typedef __attribute__((ext_vector_type(4))) float f32x4;   // MFMA C/D frag

// pack two fp32 -> two bf16, round-half-up (3 VALU)
__device__ __forceinline__ unsigned pk2(float a, float b) {
  return __builtin_amdgcn_perm(__float_as_uint(b) + 0x8000u,
                               __float_as_uint(a) + 0x8000u, 0x07060302u);
}
// pack two fp32 -> two bf16, TRUNCATE (1 VALU) — P only; bias cancels in P/l.
__device__ __forceinline__ unsigned pk2t(float a, float b) {
  return __builtin_amdgcn_perm(__float_as_uint(b), __float_as_uint(a), 0x07060302u);
}

// 2^x on the VALU (v_exp_f32 computes 2^x natively)
#if __has_builtin(__builtin_amdgcn_exp2f)
#define EXP2F(x) __builtin_amdgcn_exp2f(x)
#else
#define EXP2F(x) exp2f(x)
#endif

// ---------------------------------------------------------------------------
// Fused prep: blocks [0,1536) transpose x [b][c][n] fp32 -> xt [b][n][c] bf16;
// blocks [1536,2112) convert weights to bf16 (Q rows pre-scaled by
// SCALE*log2e so attention logits come out base-2 ready).
// ---------------------------------------------------------------------------
__global__ __launch_bounds__(256) void prep_fused(
    const float* __restrict__ x, const float* __restrict__ qw,
    const float* __restrict__ pw, unsigned short* __restrict__ xt,
    unsigned short* __restrict__ wq, unsigned short* __restrict__ pwq) {
  const int bx = blockIdx.x;
  const int tid = threadIdx.x;
  if (bx < 1536) {
    __shared__ float T[64][65];
    const int b = bx / 96, rem = bx - b * 96;
    const int c0 = (rem >> 4) * 64, n0 = (rem & 15) * 64;
    const float* xb = x + ((size_t)b * CH + c0) * NPIX + n0;
    const int rn = (tid & 15) * 4, rc = tid >> 4;
#pragma unroll
    for (int i = 0; i < 4; i++) {
      float4 v = *(const float4*)(xb + (size_t)(rc + i * 16) * NPIX + rn);
      T[rc + i * 16][rn + 0] = v.x;
      T[rc + i * 16][rn + 1] = v.y;
      T[rc + i * 16][rn + 2] = v.z;
      T[rc + i * 16][rn + 3] = v.w;
    }
    __syncthreads();
    unsigned short* xo = xt + ((size_t)b * NPIX + n0) * CH + c0;
    const int wc = (tid & 15) * 4, wn = tid >> 4;
#pragma unroll
    for (int i = 0; i < 4; i++) {
      const int n = wn + i * 16;
      uint2 p = {pk2(T[wc][n], T[wc + 1][n]), pk2(T[wc + 2][n], T[wc + 3][n])};
      *(uint2*)(xo + (size_t)n * CH + wc) = p;
    }
  } else {
    const int idx = (bx - 1536) * 256 + tid;
    if (idx < 110592) {
      float4 v = ((const float4*)qw)[idx];
      const int o = (idx * 4) / CH;  // 4 | 384: never crosses a row
      const float sc = (o < CH) ? SCALE * LOG2E : 1.0f;
      ((uint2*)wq)[idx] = (uint2){pk2(v.x * sc, v.y * sc), pk2(v.z * sc, v.w * sc)};
    } else {
      const int j = idx - 110592;
      float4 v = ((const float4*)pw)[j];
      ((uint2*)pwq)[j] = (uint2){pk2(v.x, v.y), pk2(v.z, v.w)};
    }
  }
}

// ---------------------------------------------------------------------------
// QKV GEMM v2: LDS-FREE bf16 MFMA.  Y[o, b*1024+n] = sum_c Wq[o,c]*XT[b,n,c].
// K=384 is too short for the 2-barrier LDS K-loop (12 iters; the per-iter
// vmcnt(0)+barrier drain capped it at ~210 TF, the m102 short-shape cliff).
// Instead each wave loads its MFMA fragments DIRECTLY from global (L2-hot:
// wq is 0.9 MB total; grid x = b*8+ntile so XCD = x%8 pins each xt B-slice
// to one XCD) with 1-iteration register prefetch — attn_mfma's load pattern.
// No barriers, no LDS, no waitcnt drains.
// Block 128m x 128n, 4 waves of 64x64 (4x4 frags).  V-blocks swap MFMA
// operands so C rows = consecutive pixels -> vectorized d-major stores.
// ---------------------------------------------------------------------------
__global__ __launch_bounds__(256, 3) void qkv_mfma(
    const unsigned short* __restrict__ xt, const unsigned short* __restrict__ wq,
    unsigned short* __restrict__ qb, unsigned short* __restrict__ kb,
    unsigned short* __restrict__ vtb) {
  const int bx = blockIdx.x;          // 0..127: b = bx>>3, ntile = bx&7
  const int b  = bx >> 3;
  const int n0 = (bx & 7) * 128;
  const int m0 = blockIdx.y * 128;    // 0..8
  const int qkv_t = blockIdx.y / 3;   // 0=Q, 1=K, 2=V
  const int tid = threadIdx.x, wave = tid >> 6, lane = tid & 63;
  const int wm = (wave >> 1) * 64, wn = (wave & 1) * 64;
  const int cc = lane & 15, quad = lane >> 4;

  // fragment row pointers (frag t adds t*16 rows)
  const unsigned short* arow = wq + (size_t)(m0 + wm + cc) * CH + quad * 8;
  const unsigned short* brow =
      xt + ((size_t)b * NPIX + n0 + wn + cc) * CH + quad * 8;

  f32x4 acc[4][4];
#pragma unroll
  for (int i = 0; i < 4; i++)
#pragma unroll
    for (int j = 0; j < 4; j++) acc[i][j] = (f32x4){0.f, 0.f, 0.f, 0.f};

  bf16x8 af[4], bfr[4];
#pragma unroll
  for (int t = 0; t < 4; t++) af[t] = *(const bf16x8*)(arow + (size_t)t * 16 * CH);
#pragma unroll
  for (int t = 0; t < 4; t++) bfr[t] = *(const bf16x8*)(brow + (size_t)t * 16 * CH);

#pragma unroll 2
  for (int k0 = 0; k0 < CH; k0 += 32) {
    const int k2 = (k0 + 32 < CH) ? k0 + 32 : 0;  // wrap: redundant, in-bounds
    bf16x8 naf[4], nbf[4];
#pragma unroll
    for (int t = 0; t < 4; t++)
      naf[t] = *(const bf16x8*)(arow + (size_t)t * 16 * CH + k2);
#pragma unroll
    for (int t = 0; t < 4; t++)
      nbf[t] = *(const bf16x8*)(brow + (size_t)t * 16 * CH + k2);

    if (qkv_t < 2) {
#pragma unroll
      for (int i = 0; i < 4; i++)
#pragma unroll
        for (int j = 0; j < 4; j++)
          acc[i][j] = __builtin_amdgcn_mfma_f32_16x16x32_bf16(af[i], bfr[j], acc[i][j], 0, 0, 0);
    } else {  // V: swap -> C rows = pixels, cols = weight-o
#pragma unroll
      for (int i = 0; i < 4; i++)
#pragma unroll
        for (int j = 0; j < 4; j++)
          acc[i][j] = __builtin_amdgcn_mfma_f32_16x16x32_bf16(bfr[i], af[j], acc[i][j], 0, 0, 0);
    }
#pragma unroll
    for (int t = 0; t < 4; t++) { af[t] = naf[t]; bfr[t] = nbf[t]; }
  }

  const int obase = m0 - qkv_t * CH;  // 0/128/256 within the Q/K/V segment
  if (qkv_t < 2) {
    unsigned short* dst0 = (qkv_t == 0) ? qb : kb;
#pragma unroll
    for (int mt = 0; mt < 4; mt++) {
      const int o = obase + wm + mt * 16 + quad * 4;  // [0,384)
      const int h = o >> 5, d0 = o & 31;
      unsigned short* drow = dst0 + ((size_t)(b * NHEAD + h) * NPIX) * DH + d0;
#pragma unroll
      for (int nt = 0; nt < 4; nt++) {
        const int n = n0 + wn + nt * 16 + cc;
        uint2 p = {pk2(acc[mt][nt][0], acc[mt][nt][1]),
                   pk2(acc[mt][nt][2], acc[mt][nt][3])};
        *(uint2*)(drow + (size_t)n * DH) = p;
      }
    }
  } else {
#pragma unroll
    for (int i = 0; i < 4; i++) {
      const int nbase = n0 + wn + i * 16 + quad * 4;
#pragma unroll
      for (int j = 0; j < 4; j++) {
        const int od = obase + wm + j * 16 + cc;
        const int h = od >> 5, dd = od & 31;
        unsigned short* vrow = vtb + ((size_t)(b * NHEAD + h) * DH + dd) * NPIX;
        *(uint2*)(vrow + nbase) = (uint2){pk2(acc[i][j][0], acc[i][j][1]),
                                          pk2(acc[i][j][2], acc[i][j][3])};
      }
    }
  }
}

// ---------------------------------------------------------------------------
// MFMA attention (R9 best, unchanged).  One wave = 64 queries; denominator on
// the matrix pipe (ones-MFMA over the same truncated P the PV consumes);
// truncate-pack; skewed pipeline; XCD-pinned grid.
// ---------------------------------------------------------------------------
__global__ __launch_bounds__(256, 3) void attn_mfma(
    const unsigned short* __restrict__ qb, const unsigned short* __restrict__ kb,
    const unsigned short* __restrict__ vtb, unsigned short* __restrict__ ao) {
  constexpr int PSTR = 36;  // 72 B rows: 18c mod 32 hits all 16 even residues
  __shared__ unsigned short Pbuf[4][4][16][PSTR];  // [wave][qgroup][row][keys]

  const int bh   = blockIdx.x;  // 0..191  (x-major -> XCD = bh % 8)
  const int b    = bh / NHEAD;
  const int h    = bh - b * NHEAD;
  const int tid  = threadIdx.x;
  const int wave = tid >> 6;
  const int lane = tid & 63;
  const int c    = lane & 15;
  const int Q0   = lane >> 4;
  const int q0   = blockIdx.y * 256 + wave * 64;

  bf16x8 Bq[4];
#pragma unroll
  for (int g = 0; g < 4; g++)
    Bq[g] = *(const bf16x8*)(qb + ((size_t)bh * NPIX + q0 + 16 * g + c) * DH + Q0 * 8);

  const unsigned short* kbase = kb + (size_t)bh * NPIX * DH;
  const unsigned short* vrow0 = vtb + ((size_t)bh * DH + c) * NPIX;
  const unsigned short* vrow1 = vtb + ((size_t)bh * DH + c + 16) * NPIX;

  const f32x4 zero = {0.f, 0.f, 0.f, 0.f};
  const bf16x8 zero8 = {0, 0, 0, 0, 0, 0, 0, 0};
  const short ONE = (short)0x3F80;  // bf16 1.0
  const bf16x8 ones = {ONE, ONE, ONE, ONE, ONE, ONE, ONE, ONE};

  f32x4 o0[4], o1[4], ls[4];
#pragma unroll
  for (int g = 0; g < 4; g++) { o0[g] = zero; o1[g] = zero; ls[g] = zero; }

  unsigned short* prow[4];
#pragma unroll
  for (int g = 0; g < 4; g++) prow[g] = &Pbuf[wave][g][c][0];

  bf16x8 Ka0 = *(const bf16x8*)(kbase + (size_t)c * DH + Q0 * 8);  // K(0)
  bf16x8 Ka1 = *(const bf16x8*)(kbase + (size_t)(16 + c) * DH + Q0 * 8);
  bf16x8 Vr0 = zero8, Vr1 = zero8;              // V(t-1); PV(-1) adds 0
  bf16x8 Bp[4] = {zero8, zero8, zero8, zero8};  // P(t-1)

#pragma unroll 2
  for (int kt = 0; kt < NPIX; kt += 32) {
    const int kt2 = (kt + 32) & (NPIX - 1);  // wrap on last iter (in-bounds)
    bf16x8 nKa0 = *(const bf16x8*)(kbase + (size_t)(kt2 + c) * DH + Q0 * 8);
    bf16x8 nKa1 = *(const bf16x8*)(kbase + (size_t)(kt2 + 16 + c) * DH + Q0 * 8);
    bf16x8 nVa0 = *(const bf16x8*)(vrow0 + kt + Q0 * 8);
    bf16x8 nVa1 = *(const bf16x8*)(vrow1 + kt + Q0 * 8);

    f32x4 s0[4], s1[4];
#pragma unroll
    for (int g = 0; g < 4; g++) {
      s0[g] = __builtin_amdgcn_mfma_f32_16x16x32_bf16(Ka0, Bq[g], zero, 0, 0, 0);
      s1[g] = __builtin_amdgcn_mfma_f32_16x16x32_bf16(Ka1, Bq[g], zero, 0, 0, 0);
    }

#pragma unroll
    for (int g = 0; g < 4; g++) {
      o0[g] = __builtin_amdgcn_mfma_f32_16x16x32_bf16(Vr0, Bp[g], o0[g], 0, 0, 0);
      o1[g] = __builtin_amdgcn_mfma_f32_16x16x32_bf16(Vr1, Bp[g], o1[g], 0, 0, 0);
      ls[g] = __builtin_amdgcn_mfma_f32_16x16x32_bf16(ones, Bp[g], ls[g], 0, 0, 0);
    }

#pragma unroll
    for (int g = 0; g < 4; g++) {
      float p0[4], p1[4];
#pragma unroll
      for (int r = 0; r < 4; r++) p0[r] = EXP2F(s0[g][r]);
#pragma unroll
      for (int r = 0; r < 4; r++) p1[r] = EXP2F(s1[g][r]);
      *(uint2*)(prow[g] + 4 * Q0)      = (uint2){pk2t(p0[0], p0[1]), pk2t(p0[2], p0[3])};
      *(uint2*)(prow[g] + 16 + 4 * Q0) = (uint2){pk2t(p1[0], p1[1]), pk2t(p1[2], p1[3])};
    }
#pragma unroll
    for (int g = 0; g < 4; g++) Bp[g] = *(const bf16x8*)(prow[g] + 8 * Q0);

    Ka0 = nKa0; Ka1 = nKa1; Vr0 = nVa0; Vr1 = nVa1;
  }

#pragma unroll
  for (int g = 0; g < 4; g++) {
    o0[g] = __builtin_amdgcn_mfma_f32_16x16x32_bf16(Vr0, Bp[g], o0[g], 0, 0, 0);
    o1[g] = __builtin_amdgcn_mfma_f32_16x16x32_bf16(Vr1, Bp[g], o1[g], 0, 0, 0);
    ls[g] = __builtin_amdgcn_mfma_f32_16x16x32_bf16(ones, Bp[g], ls[g], 0, 0, 0);
  }

#pragma unroll
  for (int g = 0; g < 4; g++) {
    const float inv = 1.0f / ls[g][0];  // all regs/rows identical = full l[q]
    unsigned short* op =
        ao + ((size_t)(b * NPIX + q0 + 16 * g + c)) * CH + h * DH + 4 * Q0;
    *(uint2*)op = (uint2){pk2(o0[g][0] * inv, o0[g][1] * inv),
                          pk2(o0[g][2] * inv, o0[g][3] * inv)};
    *(uint2*)(op + 16) = (uint2){pk2(o1[g][0] * inv, o1[g][1] * inv),
                                 pk2(o1[g][2] * inv, o1[g][3] * inv)};
  }
}

// ---------------------------------------------------------------------------
// Output projection v2: LDS-FREE bf16 MFMA (same rationale as qkv v2).
//   out[b][c][n] = sum_{c'} Pw[c,c'] * AO[b,n,c'] + bias[c]
// M=384 (y 0..2), N=16*1024 merged (x = b*8+ntile), 384 blocks — all
// resident in a single pass.  pw (0.3 MB) is L2-resident everywhere; each
// ao slice is read by 3 same-XCD blocks (XCD = x%8).
// ---------------------------------------------------------------------------
__global__ __launch_bounds__(256, 3) void proj_mfma(
    const unsigned short* __restrict__ ao, const unsigned short* __restrict__ pwq,
    const float* __restrict__ bias, float* __restrict__ out) {
  const int bx = blockIdx.x;
  const int b  = bx >> 3;
  const int n0 = (bx & 7) * 128;
  const int m0 = blockIdx.y * 128;
  const int tid = threadIdx.x, wave = tid >> 6, lane = tid & 63;
  const int wm = (wave >> 1) * 64, wn = (wave & 1) * 64;
  const int cc = lane & 15, quad = lane >> 4;

  const unsigned short* arow = pwq + (size_t)(m0 + wm + cc) * CH + quad * 8;
  const unsigned short* brow =
      ao + ((size_t)b * NPIX + n0 + wn + cc) * CH + quad * 8;

  f32x4 acc[4][4];
#pragma unroll
  for (int i = 0; i < 4; i++)
#pragma unroll
    for (int j = 0; j < 4; j++) acc[i][j] = (f32x4){0.f, 0.f, 0.f, 0.f};

  bf16x8 af[4], bfr[4];
#pragma unroll
  for (int t = 0; t < 4; t++) af[t] = *(const bf16x8*)(arow + (size_t)t * 16 * CH);
#pragma unroll
  for (int t = 0; t < 4; t++) bfr[t] = *(const bf16x8*)(brow + (size_t)t * 16 * CH);

#pragma unroll 2
  for (int k0 = 0; k0 < CH; k0 += 32) {
    const int k2 = (k0 + 32 < CH) ? k0 + 32 : 0;
    bf16x8 naf[4], nbf[4];
#pragma unroll
    for (int t = 0; t < 4; t++)
      naf[t] = *(const bf16x8*)(arow + (size_t)t * 16 * CH + k2);
#pragma unroll
    for (int t = 0; t < 4; t++)
      nbf[t] = *(const bf16x8*)(brow + (size_t)t * 16 * CH + k2);
#pragma unroll
    for (int i = 0; i < 4; i++)
#pragma unroll
      for (int j = 0; j < 4; j++)
        acc[i][j] = __builtin_amdgcn_mfma_f32_16x16x32_bf16(af[i], bfr[j], acc[i][j], 0, 0, 0);
#pragma unroll
    for (int t = 0; t < 4; t++) { af[t] = naf[t]; bfr[t] = nbf[t]; }
  }

#pragma unroll
  for (int mt = 0; mt < 4; mt++) {
    const int cbase = m0 + wm + mt * 16 + quad * 4;
    const float4 bi4 = *(const float4*)(bias + cbase);
#pragma unroll
    for (int nt = 0; nt < 4; nt++) {
      const int n = n0 + wn + nt * 16 + cc;
      float* op = out + ((size_t)b * CH + cbase) * NPIX + n;
      op[0 * NPIX] = acc[mt][nt][0] + bi4.x;
      op[1 * NPIX] = acc[mt][nt][1] + bi4.y;
      op[2 * NPIX] = acc[mt][nt][2] + bi4.z;
      op[3 * NPIX] = acc[mt][nt][3] + bi4.w;
    }
  }
}

extern "C" void kernel_launch(void* const* d_in, const int* in_sizes, int n_in,
                              void* d_out, int out_size, void* d_ws, size_t ws_size,
                              hipStream_t stream) {
  const float* x      = (const float*)d_in[0];  // [16,384,32,32]
  const float* qkv_w  = (const float*)d_in[1];  // [1152,384]
  const float* proj_w = (const float*)d_in[2];  // [384,384]
  const float* proj_b = (const float*)d_in[3];  // [384]

  constexpr size_t SEG = (size_t)NB * NPIX * CH;  // 6291456
  unsigned short* ws  = (unsigned short*)d_ws;
  unsigned short* xtw = ws;
  unsigned short* qbw = ws + SEG;
  unsigned short* kbw = ws + 2 * SEG;
  unsigned short* vtw = ws + 3 * SEG;
  unsigned short* aow = ws + 4 * SEG;
  unsigned short* wqw = ws + 5 * SEG;               // 442368
  unsigned short* pww = wqw + (size_t)3 * CH * CH;  // 147456

  prep_fused<<<2112, 256, 0, stream>>>(x, qkv_w, proj_w, xtw, wqw, pww);
  // grid x = b*8+ntile: XCD = x%8 pins each xt slice; y = 9 m-tiles
  qkv_mfma<<<dim3(NB * (NPIX / 128), (3 * CH) / 128), 256, 0, stream>>>(xtw, wqw, qbw, kbw, vtw);
  // grid (bh, qtile): same-bh blocks share an XCD -> K/V L2-resident
  attn_mfma<<<dim3(NB * NHEAD, NPIX / 256), 256, 0, stream>>>(qbw, kbw, vtw, aow);
  proj_mfma<<<dim3(NB * (NPIX / 128), CH / 128), 256, 0, stream>>>(aow, pww, proj_b, (float*)d_out);
}

// Round 11
// 177.817 us; speedup vs baseline: 1.2928x; 1.2928x over previous
//
#include <hip/hip_runtime.h>

// Problem constants (fixed by the reference)
constexpr int CH    = 384;    // channels
constexpr int NPIX  = 1024;   // H*W = 32*32
constexpr int NHEAD = 12;
constexpr int DH    = 32;     // head dim
constexpr int NB    = 16;     // batch
constexpr float SCALE = 0.17677669529663689f;  // 32^-0.5
constexpr float LOG2E = 1.4426950408889634f;

typedef __attribute__((ext_vector_type(8))) short bf16x8;  // 8 bf16 (4 VGPRs)
typedef __attribute__((ext_vector_type(4))) float f32x4;   // MFMA C/D frag

// Fragment-major ("swizzled") operand layout for the LDS-free GEMMs:
// a K-major matrix [R][384] is stored as [R/16][12] blocks of 512 bf16;
// within a block, lane (quad*16+cc) holds row cc, k = quad*8..+7 of the
// 32-wide k-chunk, at offset lane*8.  A fragment load is then
// base + lane*8 -> 1 KB fully coalesced per wave instruction.
// elem (r, ch):  off = ((r>>4)*12 + (ch>>5))*512 + (((ch>>3)&3)*16 + (r&15))*8 + (ch&7)

// pack two fp32 -> two bf16, round-half-up (3 VALU)
__device__ __forceinline__ unsigned pk2(float a, float b) {
  return __builtin_amdgcn_perm(__float_as_uint(b) + 0x8000u,
                               __float_as_uint(a) + 0x8000u, 0x07060302u);
}
// pack two fp32 -> two bf16, TRUNCATE (1 VALU) — P only; bias cancels in P/l.
__device__ __forceinline__ unsigned pk2t(float a, float b) {
  return __builtin_amdgcn_perm(__float_as_uint(b), __float_as_uint(a), 0x07060302u);
}

// 2^x on the VALU (v_exp_f32 computes 2^x natively)
#if __has_builtin(__builtin_amdgcn_exp2f)
#define EXP2F(x) __builtin_amdgcn_exp2f(x)
#else
#define EXP2F(x) exp2f(x)
#endif

// ---------------------------------------------------------------------------
// Fused prep: blocks [0,1536) transpose x [b][c][n] fp32 -> xt swizzled bf16
// (per batch: 64 row-blocks x 12 k-chunks); blocks [1536,2112) convert
// weights to swizzled bf16 (Q rows pre-scaled by SCALE*log2e: base-2 logits).
// ---------------------------------------------------------------------------
__global__ __launch_bounds__(256) void prep_fused(
    const float* __restrict__ x, const float* __restrict__ qw,
    const float* __restrict__ pw, unsigned short* __restrict__ xts,
    unsigned short* __restrict__ wqs, unsigned short* __restrict__ pws) {
  const int bx = blockIdx.x;
  const int tid = threadIdx.x;
  if (bx < 1536) {
    __shared__ float T[64][65];
    const int b = bx / 96, rem = bx - b * 96;
    const int c0 = (rem >> 4) * 64, n0 = (rem & 15) * 64;
    const float* xb = x + ((size_t)b * CH + c0) * NPIX + n0;
    const int rn = (tid & 15) * 4, rc = tid >> 4;
#pragma unroll
    for (int i = 0; i < 4; i++) {
      float4 v = *(const float4*)(xb + (size_t)(rc + i * 16) * NPIX + rn);
      T[rc + i * 16][rn + 0] = v.x;
      T[rc + i * 16][rn + 1] = v.y;
      T[rc + i * 16][rn + 2] = v.z;
      T[rc + i * 16][rn + 3] = v.w;
    }
    __syncthreads();
    const int wc = (tid & 15) * 4;  // channel offset within the 64-wide c tile
    const int ch = c0 + wc;         // 4 consecutive channels, j = ch&7 in {0,4}
    const int kc = ch >> 5, qd = (ch >> 3) & 3, j = ch & 7;
#pragma unroll
    for (int i = 0; i < 4; i++) {
      const int nl = (tid >> 4) + i * 16;       // local pixel row
      const int ng = n0 + nl;
      uint2 p = {pk2(T[wc][nl], T[wc + 1][nl]), pk2(T[wc + 2][nl], T[wc + 3][nl])};
      size_t off = (((size_t)b * 64 + (ng >> 4)) * 12 + kc) * 512 +
                   (qd * 16 + (ng & 15)) * 8 + j;
      *(uint2*)(xts + off) = p;
    }
  } else {
    const int idx = (bx - 1536) * 256 + tid;
    if (idx < 110592) {
      float4 v = ((const float4*)qw)[idx];
      const int o  = (idx * 4) / CH;  // 4 | 384: never crosses a row
      const int ch = (idx * 4) - o * CH;
      const float sc = (o < CH) ? SCALE * LOG2E : 1.0f;
      size_t off = (((size_t)(o >> 4)) * 12 + (ch >> 5)) * 512 +
                   (((ch >> 3) & 3) * 16 + (o & 15)) * 8 + (ch & 7);
      *(uint2*)(wqs + off) =
          (uint2){pk2(v.x * sc, v.y * sc), pk2(v.z * sc, v.w * sc)};
    } else {
      const int jdx = idx - 110592;
      float4 v = ((const float4*)pw)[jdx];
      const int o  = (jdx * 4) / CH;
      const int ch = (jdx * 4) - o * CH;
      size_t off = (((size_t)(o >> 4)) * 12 + (ch >> 5)) * 512 +
                   (((ch >> 3) & 3) * 16 + (o & 15)) * 8 + (ch & 7);
      *(uint2*)(pws + off) = (uint2){pk2(v.x, v.y), pk2(v.z, v.w)};
    }
  }
}

// ---------------------------------------------------------------------------
// QKV GEMM v3: LDS-free, SWIZZLED operands.  Y[o, b*1024+n] = Wq.XT^T.
// Every fragment load is base + lane*8 (1 KB coalesced); 1-iter register
// prefetch; no barriers, no LDS, no waitcnt drains.  Grid x = b*8+ntile
// pins each batch's xt slice to one XCD.  V-blocks swap MFMA operands so
// C rows = consecutive pixels -> vectorized d-major stores.
// ---------------------------------------------------------------------------
__global__ __launch_bounds__(256, 3) void qkv_mfma(
    const unsigned short* __restrict__ xts, const unsigned short* __restrict__ wqs,
    unsigned short* __restrict__ qb, unsigned short* __restrict__ kb,
    unsigned short* __restrict__ vtb) {
  const int bx = blockIdx.x;          // b = bx>>3, ntile = bx&7
  const int b  = bx >> 3;
  const int n0 = (bx & 7) * 128;
  const int m0 = blockIdx.y * 128;    // 0..8
  const int qkv_t = blockIdx.y / 3;   // 0=Q, 1=K, 2=V
  const int tid = threadIdx.x, wave = tid >> 6, lane = tid & 63;
  const int wm = (wave >> 1) * 64, wn = (wave & 1) * 64;
  const int cc = lane & 15, quad = lane >> 4;

  const unsigned short* abase =
      wqs + ((size_t)((m0 + wm) >> 4) * 12) * 512 + lane * 8;
  const unsigned short* bbase =
      xts + (((size_t)b * 64 + ((n0 + wn) >> 4)) * 12) * 512 + lane * 8;

  f32x4 acc[4][4];
#pragma unroll
  for (int i = 0; i < 4; i++)
#pragma unroll
    for (int j = 0; j < 4; j++) acc[i][j] = (f32x4){0.f, 0.f, 0.f, 0.f};

  bf16x8 af[4], bfr[4];
#pragma unroll
  for (int t = 0; t < 4; t++) af[t] = *(const bf16x8*)(abase + (size_t)(t * 12) * 512);
#pragma unroll
  for (int t = 0; t < 4; t++) bfr[t] = *(const bf16x8*)(bbase + (size_t)(t * 12) * 512);

#pragma unroll 2
  for (int kc = 0; kc < 12; kc++) {
    const int k2 = (kc + 1 < 12) ? kc + 1 : 0;  // wrap: redundant, in-bounds
    bf16x8 naf[4], nbf[4];
#pragma unroll
    for (int t = 0; t < 4; t++)
      naf[t] = *(const bf16x8*)(abase + (size_t)(t * 12 + k2) * 512);
#pragma unroll
    for (int t = 0; t < 4; t++)
      nbf[t] = *(const bf16x8*)(bbase + (size_t)(t * 12 + k2) * 512);

    if (qkv_t < 2) {
#pragma unroll
      for (int i = 0; i < 4; i++)
#pragma unroll
        for (int j = 0; j < 4; j++)
          acc[i][j] = __builtin_amdgcn_mfma_f32_16x16x32_bf16(af[i], bfr[j], acc[i][j], 0, 0, 0);
    } else {  // V: swap -> C rows = pixels, cols = weight-o
#pragma unroll
      for (int i = 0; i < 4; i++)
#pragma unroll
        for (int j = 0; j < 4; j++)
          acc[i][j] = __builtin_amdgcn_mfma_f32_16x16x32_bf16(bfr[i], af[j], acc[i][j], 0, 0, 0);
    }
#pragma unroll
    for (int t = 0; t < 4; t++) { af[t] = naf[t]; bfr[t] = nbf[t]; }
  }

  const int obase = m0 - qkv_t * CH;  // 0/128/256 within the Q/K/V segment
  if (qkv_t < 2) {
    unsigned short* dst0 = (qkv_t == 0) ? qb : kb;
#pragma unroll
    for (int mt = 0; mt < 4; mt++) {
      const int o = obase + wm + mt * 16 + quad * 4;  // [0,384)
      const int h = o >> 5, d0 = o & 31;
      unsigned short* drow = dst0 + ((size_t)(b * NHEAD + h) * NPIX) * DH + d0;
#pragma unroll
      for (int nt = 0; nt < 4; nt++) {
        const int n = n0 + wn + nt * 16 + cc;
        uint2 p = {pk2(acc[mt][nt][0], acc[mt][nt][1]),
                   pk2(acc[mt][nt][2], acc[mt][nt][3])};
        *(uint2*)(drow + (size_t)n * DH) = p;
      }
    }
  } else {
#pragma unroll
    for (int i = 0; i < 4; i++) {
      const int nbase = n0 + wn + i * 16 + quad * 4;
#pragma unroll
      for (int j = 0; j < 4; j++) {
        const int od = obase + wm + j * 16 + cc;
        const int h = od >> 5, dd = od & 31;
        unsigned short* vrow = vtb + ((size_t)(b * NHEAD + h) * DH + dd) * NPIX;
        *(uint2*)(vrow + nbase) = (uint2){pk2(acc[i][j][0], acc[i][j][1]),
                                          pk2(acc[i][j][2], acc[i][j][3])};
      }
    }
  }
}

// ---------------------------------------------------------------------------
// MFMA attention (R9 structure).  One wave = 64 queries; denominator on the
// matrix pipe (ones-MFMA over the same truncated P the PV consumes);
// truncate-pack; skewed pipeline; XCD-pinned grid.  ONLY change vs R9: the
// output is written in proj's fragment-major layout (DH=32 = one k-chunk;
// channel h*32+4Q0+r maps to quad_p=Q0>>1 [+2 for o1], j=4*(Q0&1)).
// ---------------------------------------------------------------------------
__global__ __launch_bounds__(256, 3) void attn_mfma(
    const unsigned short* __restrict__ qb, const unsigned short* __restrict__ kb,
    const unsigned short* __restrict__ vtb, unsigned short* __restrict__ ao) {
  constexpr int PSTR = 36;  // 72 B rows: 18c mod 32 hits all 16 even residues
  __shared__ unsigned short Pbuf[4][4][16][PSTR];  // [wave][qgroup][row][keys]

  const int bh   = blockIdx.x;  // 0..191  (x-major -> XCD = bh % 8)
  const int b    = bh / NHEAD;
  const int h    = bh - b * NHEAD;
  const int tid  = threadIdx.x;
  const int wave = tid >> 6;
  const int lane = tid & 63;
  const int c    = lane & 15;
  const int Q0   = lane >> 4;
  const int q0   = blockIdx.y * 256 + wave * 64;

  bf16x8 Bq[4];
#pragma unroll
  for (int g = 0; g < 4; g++)
    Bq[g] = *(const bf16x8*)(qb + ((size_t)bh * NPIX + q0 + 16 * g + c) * DH + Q0 * 8);

  const unsigned short* kbase = kb + (size_t)bh * NPIX * DH;
  const unsigned short* vrow0 = vtb + ((size_t)bh * DH + c) * NPIX;
  const unsigned short* vrow1 = vtb + ((size_t)bh * DH + c + 16) * NPIX;

  const f32x4 zero = {0.f, 0.f, 0.f, 0.f};
  const bf16x8 zero8 = {0, 0, 0, 0, 0, 0, 0, 0};
  const short ONE = (short)0x3F80;  // bf16 1.0
  const bf16x8 ones = {ONE, ONE, ONE, ONE, ONE, ONE, ONE, ONE};

  f32x4 o0[4], o1[4], ls[4];
#pragma unroll
  for (int g = 0; g < 4; g++) { o0[g] = zero; o1[g] = zero; ls[g] = zero; }

  unsigned short* prow[4];
#pragma unroll
  for (int g = 0; g < 4; g++) prow[g] = &Pbuf[wave][g][c][0];

  bf16x8 Ka0 = *(const bf16x8*)(kbase + (size_t)c * DH + Q0 * 8);  // K(0)
  bf16x8 Ka1 = *(const bf16x8*)(kbase + (size_t)(16 + c) * DH + Q0 * 8);
  bf16x8 Vr0 = zero8, Vr1 = zero8;              // V(t-1); PV(-1) adds 0
  bf16x8 Bp[4] = {zero8, zero8, zero8, zero8};  // P(t-1)

#pragma unroll 2
  for (int kt = 0; kt < NPIX; kt += 32) {
    const int kt2 = (kt + 32) & (NPIX - 1);  // wrap on last iter (in-bounds)
    bf16x8 nKa0 = *(const bf16x8*)(kbase + (size_t)(kt2 + c) * DH + Q0 * 8);
    bf16x8 nKa1 = *(const bf16x8*)(kbase + (size_t)(kt2 + 16 + c) * DH + Q0 * 8);
    bf16x8 nVa0 = *(const bf16x8*)(vrow0 + kt + Q0 * 8);
    bf16x8 nVa1 = *(const bf16x8*)(vrow1 + kt + Q0 * 8);

    f32x4 s0[4], s1[4];
#pragma unroll
    for (int g = 0; g < 4; g++) {
      s0[g] = __builtin_amdgcn_mfma_f32_16x16x32_bf16(Ka0, Bq[g], zero, 0, 0, 0);
      s1[g] = __builtin_amdgcn_mfma_f32_16x16x32_bf16(Ka1, Bq[g], zero, 0, 0, 0);
    }

#pragma unroll
    for (int g = 0; g < 4; g++) {
      o0[g] = __builtin_amdgcn_mfma_f32_16x16x32_bf16(Vr0, Bp[g], o0[g], 0, 0, 0);
      o1[g] = __builtin_amdgcn_mfma_f32_16x16x32_bf16(Vr1, Bp[g], o1[g], 0, 0, 0);
      ls[g] = __builtin_amdgcn_mfma_f32_16x16x32_bf16(ones, Bp[g], ls[g], 0, 0, 0);
    }

#pragma unroll
    for (int g = 0; g < 4; g++) {
      float p0[4], p1[4];
#pragma unroll
      for (int r = 0; r < 4; r++) p0[r] = EXP2F(s0[g][r]);
#pragma unroll
      for (int r = 0; r < 4; r++) p1[r] = EXP2F(s1[g][r]);
      *(uint2*)(prow[g] + 4 * Q0)      = (uint2){pk2t(p0[0], p0[1]), pk2t(p0[2], p0[3])};
      *(uint2*)(prow[g] + 16 + 4 * Q0) = (uint2){pk2t(p1[0], p1[1]), pk2t(p1[2], p1[3])};
    }
#pragma unroll
    for (int g = 0; g < 4; g++) Bp[g] = *(const bf16x8*)(prow[g] + 8 * Q0);

    Ka0 = nKa0; Ka1 = nKa1; Vr0 = nVa0; Vr1 = nVa1;
  }

#pragma unroll
  for (int g = 0; g < 4; g++) {
    o0[g] = __builtin_amdgcn_mfma_f32_16x16x32_bf16(Vr0, Bp[g], o0[g], 0, 0, 0);
    o1[g] = __builtin_amdgcn_mfma_f32_16x16x32_bf16(Vr1, Bp[g], o1[g], 0, 0, 0);
    ls[g] = __builtin_amdgcn_mfma_f32_16x16x32_bf16(ones, Bp[g], ls[g], 0, 0, 0);
  }

  // store normalized O in proj's fragment-major layout:
  // row-block rb = (q0>>4)+g, k-chunk = h, row-in-block = c.
#pragma unroll
  for (int g = 0; g < 4; g++) {
    const float inv = 1.0f / ls[g][0];  // all regs/rows identical = full l[q]
    unsigned short* op = ao +
        (((size_t)b * 64 + (q0 >> 4) + g) * 12 + h) * 512 + c * 8 + 4 * (Q0 & 1);
    *(uint2*)(op + (Q0 >> 1) * 128) =
        (uint2){pk2(o0[g][0] * inv, o0[g][1] * inv),
                pk2(o0[g][2] * inv, o0[g][3] * inv)};
    *(uint2*)(op + (2 + (Q0 >> 1)) * 128) =
        (uint2){pk2(o1[g][0] * inv, o1[g][1] * inv),
                pk2(o1[g][2] * inv, o1[g][3] * inv)};
  }
}

// ---------------------------------------------------------------------------
// Output projection v3: LDS-free, SWIZZLED operands (pw from prep, ao from
// attn).  out[b][c][n] = sum Pw[c,c']*AO[b,n,c'] + bias[c].
// Grid x = b*8+ntile (XCD pin), y = 3 m-tiles; 384 blocks, single pass.
// ---------------------------------------------------------------------------
__global__ __launch_bounds__(256, 3) void proj_mfma(
    const unsigned short* __restrict__ aos, const unsigned short* __restrict__ pws,
    const float* __restrict__ bias, float* __restrict__ out) {
  const int bx = blockIdx.x;
  const int b  = bx >> 3;
  const int n0 = (bx & 7) * 128;
  const int m0 = blockIdx.y * 128;
  const int tid = threadIdx.x, wave = tid >> 6, lane = tid & 63;
  const int wm = (wave >> 1) * 64, wn = (wave & 1) * 64;
  const int cc = lane & 15, quad = lane >> 4;

  const unsigned short* abase =
      pws + ((size_t)((m0 + wm) >> 4) * 12) * 512 + lane * 8;
  const unsigned short* bbase =
      aos + (((size_t)b * 64 + ((n0 + wn) >> 4)) * 12) * 512 + lane * 8;

  f32x4 acc[4][4];
#pragma unroll
  for (int i = 0; i < 4; i++)
#pragma unroll
    for (int j = 0; j < 4; j++) acc[i][j] = (f32x4){0.f, 0.f, 0.f, 0.f};

  bf16x8 af[4], bfr[4];
#pragma unroll
  for (int t = 0; t < 4; t++) af[t] = *(const bf16x8*)(abase + (size_t)(t * 12) * 512);
#pragma unroll
  for (int t = 0; t < 4; t++) bfr[t] = *(const bf16x8*)(bbase + (size_t)(t * 12) * 512);

#pragma unroll 2
  for (int kc = 0; kc < 12; kc++) {
    const int k2 = (kc + 1 < 12) ? kc + 1 : 0;
    bf16x8 naf[4], nbf[4];
#pragma unroll
    for (int t = 0; t < 4; t++)
      naf[t] = *(const bf16x8*)(abase + (size_t)(t * 12 + k2) * 512);
#pragma unroll
    for (int t = 0; t < 4; t++)
      nbf[t] = *(const bf16x8*)(bbase + (size_t)(t * 12 + k2) * 512);
#pragma unroll
    for (int i = 0; i < 4; i++)
#pragma unroll
      for (int j = 0; j < 4; j++)
        acc[i][j] = __builtin_amdgcn_mfma_f32_16x16x32_bf16(af[i], bfr[j], acc[i][j], 0, 0, 0);
#pragma unroll
    for (int t = 0; t < 4; t++) { af[t] = naf[t]; bfr[t] = nbf[t]; }
  }

#pragma unroll
  for (int mt = 0; mt < 4; mt++) {
    const int cbase = m0 + wm + mt * 16 + quad * 4;
    const float4 bi4 = *(const float4*)(bias + cbase);
#pragma unroll
    for (int nt = 0; nt < 4; nt++) {
      const int n = n0 + wn + nt * 16 + cc;
      float* op = out + ((size_t)b * CH + cbase) * NPIX + n;
      op[0 * NPIX] = acc[mt][nt][0] + bi4.x;
      op[1 * NPIX] = acc[mt][nt][1] + bi4.y;
      op[2 * NPIX] = acc[mt][nt][2] + bi4.z;
      op[3 * NPIX] = acc[mt][nt][3] + bi4.w;
    }
  }
}

extern "C" void kernel_launch(void* const* d_in, const int* in_sizes, int n_in,
                              void* d_out, int out_size, void* d_ws, size_t ws_size,
                              hipStream_t stream) {
  const float* x      = (const float*)d_in[0];  // [16,384,32,32]
  const float* qkv_w  = (const float*)d_in[1];  // [1152,384]
  const float* proj_w = (const float*)d_in[2];  // [384,384]
  const float* proj_b = (const float*)d_in[3];  // [384]

  constexpr size_t SEG = (size_t)NB * NPIX * CH;  // 6291456
  unsigned short* ws  = (unsigned short*)d_ws;
  unsigned short* xtw = ws;                         // swizzled
  unsigned short* qbw = ws + SEG;
  unsigned short* kbw = ws + 2 * SEG;
  unsigned short* vtw = ws + 3 * SEG;
  unsigned short* aow = ws + 4 * SEG;               // swizzled
  unsigned short* wqw = ws + 5 * SEG;               // swizzled, 442368
  unsigned short* pww = wqw + (size_t)3 * CH * CH;  // swizzled, 147456

  prep_fused<<<2112, 256, 0, stream>>>(x, qkv_w, proj_w, xtw, wqw, pww);
  // grid x = b*8+ntile: XCD = x%8 pins each xt slice; y = 9 m-tiles
  qkv_mfma<<<dim3(NB * (NPIX / 128), (3 * CH) / 128), 256, 0, stream>>>(xtw, wqw, qbw, kbw, vtw);
  // grid (bh, qtile): same-bh blocks share an XCD -> K/V L2-resident
  attn_mfma<<<dim3(NB * NHEAD, NPIX / 256), 256, 0, stream>>>(qbw, kbw, vtw, aow);
  proj_mfma<<<dim3(NB * (NPIX / 128), CH / 128), 256, 0, stream>>>(aow, pww, proj_b, (float*)d_out);
}